// Round 5
// baseline (1529.022 us; speedup 1.0000x reference)
//
#include <hip/hip_runtime.h>
#include <hip/hip_bf16.h>
#include <stdint.h>

// Problem constants (fixed by the reference)
#define N_NODES 50000
#define N_EDGES 1600000
#define IN_DIM  1024
#define HID     2048
#define OUTC    3
#define M_PAD   50048   // 391 * 128 — M padded to GEMM row tile
#define BN_EPS  1e-5f

#define SCAN_CH 512
#define NCH     98      // ceil(50000/512)

// agg1 (r0 structure): 2 x 512-feat panels, wave-per-node, 8-deep edge unroll.
#define NPANEL  2
#define PFEAT   512
#define DUMMY_SRC N_NODES                 // padding edges point at zero row 50000
#define E_PAD_MAX (N_EDGES + 3 * N_NODES + 64) // CSR rows padded to x4, + slack

// gemm1 tile geometry: 128x256, BK=64, 8 waves, 3-buffer LDS ring
#define BM 128
#define BN 256
#define BK 64
#define NKT (IN_DIM / BK)    // 16 K-tiles
#define GX (HID / BN)        // 8
#define GY (M_PAD / BM)      // 391
#define NWG (GX * GY)        // 3128 (divisible by 8)
#define CPX (NWG / 8)        // 391

typedef __bf16 bf16_t;
typedef __bf16 bf16x4_t __attribute__((ext_vector_type(4)));
typedef __bf16 bf16x8_t __attribute__((ext_vector_type(8)));
typedef float  f32x4_t  __attribute__((ext_vector_type(4)));

// async global->LDS, 16B per lane. LDS dest is wave-uniform base + lane*16 (linear).
__device__ __forceinline__ void gl2lds16(const void* g, void* l) {
  __builtin_amdgcn_global_load_lds((const __attribute__((address_space(1))) uint32_t*)g,
                                   (__attribute__((address_space(3))) uint32_t*)l,
                                   16, 0, 0);
}

// ---------- degree histograms ----------
__global__ void k_hist(const int* __restrict__ src, const int* __restrict__ dst,
                       int* out_cnt, int* in_cnt) {
  int e = blockIdx.x * 256 + threadIdx.x;
  if (e < N_EDGES) {
    atomicAdd(&out_cnt[src[e]], 1);
    atomicAdd(&in_cnt[dst[e]], 1);
  }
}

// ---------- degree norms: clip(deg,1)^-0.5 (RAW degrees) ----------
__global__ void k_norms(const int* __restrict__ out_cnt, const int* __restrict__ in_cnt,
                        float* out_norm, float* in_norm) {
  int i = blockIdx.x * 256 + threadIdx.x;
  if (i < N_NODES) {
    out_norm[i] = rsqrtf((float)max(out_cnt[i], 1));
    in_norm[i]  = rsqrtf((float)max(in_cnt[i], 1));
  }
}

// ---------- exclusive scan of PADDED in-degrees (3-phase) ----------
__global__ void k_scan1(const int* __restrict__ deg, int* incl, int* partial) {
  __shared__ int s[SCAN_CH];
  int tid = threadIdx.x;
  int i = blockIdx.x * SCAN_CH + tid;
  int v = (i < N_NODES) ? ((deg[i] + 3) & ~3) : 0;
  s[tid] = v;
  for (int off = 1; off < SCAN_CH; off <<= 1) {
    __syncthreads();
    int x = (tid >= off) ? s[tid - off] : 0;
    __syncthreads();
    s[tid] += x;
  }
  __syncthreads();
  if (i < N_NODES) incl[i] = s[tid];
  if (tid == SCAN_CH - 1) partial[blockIdx.x] = s[tid];
}

__global__ void k_scan2(const int* __restrict__ partial, int* chunk_off, int* row_ptr) {
  if (threadIdx.x == 0 && blockIdx.x == 0) {
    int run = 0;
    for (int b = 0; b < NCH; b++) { chunk_off[b] = run; run += partial[b]; }
    row_ptr[N_NODES] = run;   // == padded edge count
  }
}

__global__ void k_scan3(const int* __restrict__ deg, const int* __restrict__ incl,
                        const int* __restrict__ chunk_off, int* row_ptr, int* cursor) {
  int i = blockIdx.x * SCAN_CH + threadIdx.x;
  if (i < N_NODES) {
    int dp = (deg[i] + 3) & ~3;
    int e = chunk_off[blockIdx.x] + incl[i] - dp;
    row_ptr[i] = e;
    cursor[i]  = e;
  }
}

// ---------- CSR fill (bucket by dst); padding slots filled by k_pad ----------
__global__ void k_fill(const int* __restrict__ src, const int* __restrict__ dst,
                       int* cursor, int* csr_src) {
  int e = blockIdx.x * 256 + threadIdx.x;
  if (e < N_EDGES) {
    int p = atomicAdd(&cursor[dst[e]], 1);
    csr_src[p] = src[e];
  }
}

// ---------- fill row-padding slots with the dummy (zero) source node ----------
__global__ void k_pad(const int* __restrict__ in_cnt, const int* __restrict__ row_ptr,
                      int* csr_src) {
  int i = blockIdx.x * 256 + threadIdx.x;
  if (i < N_NODES) {
    int d = in_cnt[i], dp = (d + 3) & ~3;
    int base = row_ptr[i];
    for (int j = d; j < dp; j++) csr_src[base + j] = DUMMY_SRC;
  }
}

// ---------- convert features, node-major: xb[n][1024] = bf16(in_feat*out_norm) ----------
// rows >= N_NODES (incl. the dummy row 50000) are zero
__global__ void k_conv(const float* __restrict__ in_feat, const float* __restrict__ out_norm,
                       bf16_t* __restrict__ xb) {
  int node = blockIdx.x, tid = threadIdx.x;
  bf16x4_t o;
  if (node < N_NODES) {
    float on = out_norm[node];
    float4 v = *(const float4*)(in_feat + (size_t)node * IN_DIM + tid * 4);
    o[0] = (bf16_t)(v.x * on); o[1] = (bf16_t)(v.y * on);
    o[2] = (bf16_t)(v.z * on); o[3] = (bf16_t)(v.w * on);
  } else {
    o[0] = (bf16_t)0.f; o[1] = (bf16_t)0.f; o[2] = (bf16_t)0.f; o[3] = (bf16_t)0.f;
  }
  *(bf16x4_t*)(xb + (size_t)node * IN_DIM + tid * 4) = o;
}

// ---------- layer-1 aggregation (r0 structure, best measured: 440us) ----------
// grid = (M_PAD/2, NPANEL); 128 threads = 2 waves = 2 nodes of the SAME panel.
// Wave: 64 lanes x bf16x8 = 512 feats of its node; 8-deep edge unroll.
__global__ void k_agg1(const bf16_t* __restrict__ xb, const int* __restrict__ row_ptr,
                       const int* __restrict__ csr_src, const float* __restrict__ in_norm,
                       bf16_t* __restrict__ aggb) {
  int node = blockIdx.x * 2 + (threadIdx.x >> 6);
  int lane = threadIdx.x & 63;
  int f0 = blockIdx.y * PFEAT + lane * 8;
  float acc[8];
#pragma unroll
  for (int j = 0; j < 8; j++) acc[j] = 0.f;
  float inn = 0.f;
  if (node < N_NODES) {
    int beg = row_ptr[node], end = row_ptr[node + 1];
    int e = beg;
    for (; e + 8 <= end; e += 8) {
      int s[8];
#pragma unroll
      for (int u = 0; u < 8; u++) s[u] = csr_src[e + u];
      bf16x8_t v[8];
#pragma unroll
      for (int u = 0; u < 8; u++)
        v[u] = *(const bf16x8_t*)(xb + (size_t)s[u] * IN_DIM + f0);
#pragma unroll
      for (int u = 0; u < 8; u++)
#pragma unroll
        for (int j = 0; j < 8; j++) acc[j] += (float)v[u][j];
    }
    for (; e + 2 <= end; e += 2) {
      int s0 = csr_src[e], s1 = csr_src[e + 1];
      bf16x8_t v0 = *(const bf16x8_t*)(xb + (size_t)s0 * IN_DIM + f0);
      bf16x8_t v1 = *(const bf16x8_t*)(xb + (size_t)s1 * IN_DIM + f0);
#pragma unroll
      for (int j = 0; j < 8; j++) acc[j] += (float)v0[j];
#pragma unroll
      for (int j = 0; j < 8; j++) acc[j] += (float)v1[j];
    }
    if (e < end) {
      int s0 = csr_src[e];
      bf16x8_t v0 = *(const bf16x8_t*)(xb + (size_t)s0 * IN_DIM + f0);
#pragma unroll
      for (int j = 0; j < 8; j++) acc[j] += (float)v0[j];
    }
    inn = in_norm[node];
  }
  bf16x8_t o;
#pragma unroll
  for (int j = 0; j < 8; j++) o[j] = (bf16_t)(acc[j] * inn);
  __builtin_nontemporal_store(o, (bf16x8_t*)(aggb + (size_t)node * IN_DIM + f0));
}

// ---------- W1 [K=1024][N=2048] fp32 -> W1t [N][K] bf16, LDS-tiled transpose ----------
__global__ void k_w1t(const float* __restrict__ W1, bf16_t* __restrict__ W1t) {
  __shared__ float tile[32][33];
  int k0 = blockIdx.x * 32, n0 = blockIdx.y * 32;
  int tx = threadIdx.x & 31, ty = threadIdx.x >> 5;   // 32 x 8
#pragma unroll
  for (int r = 0; r < 32; r += 8)
    tile[ty + r][tx] = W1[(size_t)(k0 + ty + r) * HID + n0 + tx];
  __syncthreads();
#pragma unroll
  for (int r = 0; r < 32; r += 8)
    W1t[(size_t)(n0 + ty + r) * IN_DIM + k0 + tx] = (bf16_t)tile[tx][ty + r];
}

// ---------- GEMM1: h1 = relu(agg @ W1 + b1) + fused BN column stats ----------
// NEW: 128x256 tile, BK=64, 8 waves (2M x 4N), 3-buffer LDS ring (144 KiB),
// counted s_waitcnt vmcnt(12/6/0) across raw s_barriers so prefetch loads stay in
// flight (the m97 2-barrier structure drains vmcnt(0) every K-step — its ~20% stall).
// LDS bank swizzle: element (row, 16B-slot s) stored at slot s^(row&7); applied to
// the pre-swizzled GLOBAL source of gl2lds AND to the ds_read address (G21).
__global__ void __launch_bounds__(512, 1)
k_gemm1(const bf16_t* __restrict__ A, const bf16_t* __restrict__ Bt,
        const float* __restrict__ b1, bf16_t* __restrict__ C,
        float* __restrict__ colsum, float* __restrict__ colsq) {
  __shared__ bf16_t sA[3][BM * BK];   // 3 x 16 KiB
  __shared__ bf16_t sB[3][BN * BK];   // 3 x 32 KiB   (total 144 KiB)

  int bid = blockIdx.x;
  int wg  = (bid & 7) * CPX + (bid >> 3);   // XCD-chunked bijective swizzle:
  int tx  = wg % GX, ty = wg / GX;          // each XCD gets a contiguous run of
  const int m0 = ty * BM, n0 = tx * BN;     // row-panels -> A panel + all B in its L2

  int tid = threadIdx.x;
  int wid = tid >> 6, ln = tid & 63;
  int lr = ln >> 3, seg = ln & 7;           // staging: lane row-in-8, 16B slot
  int wr = wid >> 2, wc = wid & 3;          // wave grid 2(M) x 4(N)
  int fr = ln & 15, fq = ln >> 4;           // fragment row/col, k-quad

  f32x4_t acc[4][4];
#pragma unroll
  for (int i = 0; i < 4; i++)
#pragma unroll
    for (int j = 0; j < 4; j++) { acc[i][j][0]=0.f; acc[i][j][1]=0.f; acc[i][j][2]=0.f; acc[i][j][3]=0.f; }

  // stage one K-tile (6 gl2lds per thread: A x2, B x4); dest linear, source pre-swizzled
  auto STAGE = [&](int buf, int kt) {
#pragma unroll
    for (int i = 0; i < 2; i++) {           // A rows: wave covers [wid*16, wid*16+16)
      int R = wid * 16 + i * 8;
      int row = R + lr;
      int ss = seg ^ (row & 7);
      gl2lds16(A + (size_t)(m0 + row) * IN_DIM + kt + ss * 8,
               (char*)&sA[buf][0] + R * 128 + ln * 16);
    }
#pragma unroll
    for (int i = 0; i < 4; i++) {           // B rows(cols): wave covers [wid*32, wid*32+32)
      int R = wid * 32 + i * 8;
      int row = R + lr;
      int ss = seg ^ (row & 7);
      gl2lds16(Bt + (size_t)(n0 + row) * IN_DIM + kt + ss * 8,
               (char*)&sB[buf][0] + R * 128 + ln * 16);
    }
  };

  // prologue: tiles 0,1 in flight
  STAGE(0, 0);
  STAGE(1, BK);

  for (int t = 0; t < NKT; t++) {
    int r = t % 3;
    if (t + 2 < NKT) {
      STAGE((t + 2) % 3, (t + 2) * BK);     // ring slot free: last read 2 iters ago
      __builtin_amdgcn_sched_barrier(0);
      asm volatile("s_waitcnt vmcnt(12)" ::: "memory");  // tile t landed; t+1,t+2 in flight
    } else if (t + 1 < NKT) {
      asm volatile("s_waitcnt vmcnt(6)" ::: "memory");
    } else {
      asm volatile("s_waitcnt vmcnt(0)" ::: "memory");
    }
    __builtin_amdgcn_sched_barrier(0);
    __builtin_amdgcn_s_barrier();           // barrier 1: tile t visible to all waves
    __builtin_amdgcn_sched_barrier(0);

    const char* pa = (const char*)&sA[r][0];
    const char* pb = (const char*)&sB[r][0];
    bf16x8_t a[2][2], bfrag[4][2];
#pragma unroll
    for (int i = 0; i < 2; i++) {
      int row = wr * 64 + i * 32;           // load 2 row-pairs below (i*16 split)
      (void)row;
    }
    // A frags: rows wr*64 + i*16 + fr, k-slot s = ks*4 + fq, swizzled slot s^(row&7)
    bf16x8_t af[4][2];
#pragma unroll
    for (int i = 0; i < 4; i++) {
      int row = wr * 64 + i * 16 + fr;
#pragma unroll
      for (int ks = 0; ks < 2; ks++) {
        int s = ks * 4 + fq;
        af[i][ks] = *(const bf16x8_t*)(pa + row * 128 + ((s ^ (row & 7)) << 4));
      }
    }
#pragma unroll
    for (int j = 0; j < 4; j++) {
      int col = wc * 64 + j * 16 + fr;
#pragma unroll
      for (int ks = 0; ks < 2; ks++) {
        int s = ks * 4 + fq;
        bfrag[j][ks] = *(const bf16x8_t*)(pb + col * 128 + ((s ^ (col & 7)) << 4));
      }
    }
    asm volatile("s_waitcnt lgkmcnt(0)" ::: "memory");
    __builtin_amdgcn_sched_barrier(0);      // rule 18: keep MFMA below the wait
    __builtin_amdgcn_s_barrier();           // barrier 2: all reads of slot r done;
    __builtin_amdgcn_sched_barrier(0);      // next iter may overwrite it while MFMAs run
    __builtin_amdgcn_s_setprio(1);
#pragma unroll
    for (int i = 0; i < 4; i++)
#pragma unroll
      for (int j = 0; j < 4; j++) {
        acc[i][j] = __builtin_amdgcn_mfma_f32_16x16x32_bf16(af[i][0], bfrag[j][0], acc[i][j], 0, 0, 0);
        acc[i][j] = __builtin_amdgcn_mfma_f32_16x16x32_bf16(af[i][1], bfrag[j][1], acc[i][j], 0, 0, 0);
      }
    __builtin_amdgcn_s_setprio(0);
    (void)a;
  }

  // epilogue: C/D layout col = ln&15, row = (ln>>4)*4 + reg ; bias, relu, nt bf16 store,
  // fused BN column stats (masked to valid rows), xor-shuffle reduce over k-quads
#pragma unroll
  for (int j = 0; j < 4; j++) {
    int col = n0 + wc * 64 + j * 16 + fr;
    float bias = b1[col];
    float s = 0.f, ss = 0.f;
#pragma unroll
    for (int i = 0; i < 4; i++) {
#pragma unroll
      for (int rr = 0; rr < 4; rr++) {
        int row = m0 + wr * 64 + i * 16 + fq * 4 + rr;
        float v = acc[i][j][rr] + bias;
        v = v > 0.f ? v : 0.f;
        bf16_t bv = (bf16_t)v;
        __builtin_nontemporal_store(*(short*)&bv, (short*)&C[(size_t)row * HID + col]);
        if (row < N_NODES) { s += v; ss += v * v; }
      }
    }
    s  += __shfl_xor(s, 16);  s  += __shfl_xor(s, 32);
    ss += __shfl_xor(ss, 16); ss += __shfl_xor(ss, 32);
    if (fq == 0) {
      atomicAdd(&colsum[col], s);
      atomicAdd(&colsq[col], ss);
    }
  }
}

// ---------- fold BN into Wout: cw[f,o] = rs[f]*Wout[f,o]; mrs[f] = mean[f]*rs[f] ----------
__global__ void k_bnfin(const float* __restrict__ colsum, const float* __restrict__ colsq,
                        const float* __restrict__ Wout,
                        float* cw0, float* cw1, float* cw2, float* mrs) {
  int f = blockIdx.x * 256 + threadIdx.x;
  if (f < HID) {
    float mean = colsum[f] * (1.f / N_NODES);
    float var  = colsq[f] * (1.f / N_NODES) - mean * mean;
    float rs   = rsqrtf(var + BN_EPS);
    cw0[f] = rs * Wout[f * 3 + 0];
    cw1[f] = rs * Wout[f * 3 + 1];
    cw2[f] = rs * Wout[f * 3 + 2];
    mrs[f] = mean * rs;
  }
}

// ---------- ct[o] = sum_f mrs[f]*Wout[f,o] ----------
__global__ void k_ct(const float* __restrict__ mrs, const float* __restrict__ Wout, float* ct) {
  __shared__ float red[3][256];
  int tid = threadIdx.x;
  float s0 = 0.f, s1 = 0.f, s2 = 0.f;
  for (int f = tid; f < HID; f += 256) {
    float m = mrs[f];
    s0 += m * Wout[f * 3 + 0];
    s1 += m * Wout[f * 3 + 1];
    s2 += m * Wout[f * 3 + 2];
  }
  red[0][tid] = s0; red[1][tid] = s1; red[2][tid] = s2;
  __syncthreads();
  for (int off = 128; off; off >>= 1) {
    if (tid < off) {
      red[0][tid] += red[0][tid + off];
      red[1][tid] += red[1][tid + off];
      red[2][tid] += red[2][tid + off];
    }
    __syncthreads();
  }
  if (tid == 0) { ct[0] = red[0][0]; ct[1] = red[1][0]; ct[2] = red[2][0]; }
}

// ---------- t[n] = out_norm[n] * (h_bn[n] @ Wout) via cw/ct ----------
__global__ void k_tmat(const bf16_t* __restrict__ h1, const float* __restrict__ cw0,
                       const float* __restrict__ cw1, const float* __restrict__ cw2,
                       const float* __restrict__ ct, const float* __restrict__ out_norm,
                       float4* __restrict__ t4) {
  int n = blockIdx.x, tid = threadIdx.x;
  int f0 = tid * 8;
  bf16x8_t hv = *(const bf16x8_t*)(h1 + (size_t)n * HID + f0);
  float s0 = 0.f, s1 = 0.f, s2 = 0.f;
#pragma unroll
  for (int j = 0; j < 8; j++) {
    float h = (float)hv[j];
    s0 += h * cw0[f0 + j];
    s1 += h * cw1[f0 + j];
    s2 += h * cw2[f0 + j];
  }
#pragma unroll
  for (int off = 32; off; off >>= 1) {
    s0 += __shfl_down(s0, off);
    s1 += __shfl_down(s1, off);
    s2 += __shfl_down(s2, off);
  }
  __shared__ float red[3][4];
  int wv = tid >> 6, ln = tid & 63;
  if (ln == 0) { red[0][wv] = s0; red[1][wv] = s1; red[2][wv] = s2; }
  __syncthreads();
  if (tid == 0) {
    float r0 = red[0][0] + red[0][1] + red[0][2] + red[0][3];
    float r1 = red[1][0] + red[1][1] + red[1][2] + red[1][3];
    float r2 = red[2][0] + red[2][1] + red[2][2] + red[2][3];
    float on = out_norm[n];
    t4[n] = make_float4(on * (r0 - ct[0]), on * (r1 - ct[1]), on * (r2 - ct[2]), 0.f);
  }
}

// ---------- layer-2 aggregation (3 feats) + bias + softmax ----------
__global__ void k_out(const int* __restrict__ row_ptr, const int* __restrict__ csr_src,
                      const float4* __restrict__ t4, const float* __restrict__ in_norm,
                      const float* __restrict__ bout, float* __restrict__ out) {
  int i = blockIdx.x * 256 + threadIdx.x;
  if (i >= N_NODES) return;
  float a0 = 0.f, a1 = 0.f, a2 = 0.f;
  int beg = row_ptr[i], end = row_ptr[i + 1];
  for (int e = beg; e < end; e++) {
    float4 tv = t4[csr_src[e]];
    a0 += tv.x; a1 += tv.y; a2 += tv.z;
  }
  float inn = in_norm[i];
  float l0 = inn * a0 + bout[0];
  float l1 = inn * a1 + bout[1];
  float l2 = inn * a2 + bout[2];
  float m = fmaxf(l0, fmaxf(l1, l2));
  float e0 = expf(l0 - m), e1 = expf(l1 - m), e2 = expf(l2 - m);
  float rs = 1.f / (e0 + e1 + e2);
  out[i * 3 + 0] = e0 * rs;
  out[i * 3 + 1] = e1 * rs;
  out[i * 3 + 2] = e2 * rs;
}

extern "C" void kernel_launch(void* const* d_in, const int* in_sizes, int n_in,
                              void* d_out, int out_size, void* d_ws, size_t ws_size,
                              hipStream_t stream) {
  const float* in_feat = (const float*)d_in[0];
  const int*   src     = (const int*)d_in[1];
  const int*   dst     = (const int*)d_in[2];
  const float* W1      = (const float*)d_in[3];
  const float* b1      = (const float*)d_in[4];
  const float* Wout    = (const float*)d_in[5];
  const float* bout    = (const float*)d_in[6];
  float* out = (float*)d_out;

  char* p = (char*)d_ws;
  auto alloc = [&](size_t bytes) { char* r = p; p += (bytes + 255) & ~(size_t)255; return r; };
  bf16_t* h1      = (bf16_t*)alloc((size_t)M_PAD * HID * 2);      // 205 MB
  bf16_t* aggb    = (bf16_t*)alloc((size_t)M_PAD * IN_DIM * 2);   // 102.5 MB
  bf16_t* xb      = (bf16_t*)alloc((size_t)M_PAD * IN_DIM * 2);   // 102.5 MB node-major
  bf16_t* W1t     = (bf16_t*)alloc((size_t)HID * IN_DIM * 2);     // 4 MB
  int* csr_src    = (int*)alloc((size_t)E_PAD_MAX * 4);           // 7 MB (padded + slack)
  int* row_ptr    = (int*)alloc((size_t)(N_NODES + 1) * 4);
  int* cursor     = (int*)alloc((size_t)N_NODES * 4);
  int* incl       = (int*)alloc((size_t)N_NODES * 4);
  int* partial    = (int*)alloc((size_t)NCH * 4);
  int* chunk_off  = (int*)alloc((size_t)NCH * 4);
  int* out_cnt    = (int*)alloc((size_t)N_NODES * 4);
  int* in_cnt     = (int*)alloc((size_t)N_NODES * 4);
  float* out_norm = (float*)alloc((size_t)N_NODES * 4);
  float* in_norm  = (float*)alloc((size_t)N_NODES * 4);
  float* colsum   = (float*)alloc((size_t)HID * 4);
  float* colsq    = (float*)alloc((size_t)HID * 4);
  float* cw0      = (float*)alloc((size_t)HID * 4);
  float* cw1      = (float*)alloc((size_t)HID * 4);
  float* cw2      = (float*)alloc((size_t)HID * 4);
  float* mrs      = (float*)alloc((size_t)HID * 4);
  float* ct       = (float*)alloc(4 * 4);
  float4* t4      = (float4*)alloc((size_t)M_PAD * 16);

  // ws is poisoned 0xAA each call — zero what needs zeroing
  hipMemsetAsync(out_cnt, 0, (size_t)N_NODES * 4, stream);
  hipMemsetAsync(in_cnt,  0, (size_t)N_NODES * 4, stream);
  hipMemsetAsync(colsum,  0, (size_t)HID * 4, stream);
  hipMemsetAsync(colsq,   0, (size_t)HID * 4, stream);
  hipMemsetAsync(t4 + N_NODES, 0, (size_t)(M_PAD - N_NODES) * 16, stream); // dummy t4 rows

  k_hist <<<(N_EDGES + 255) / 256, 256, 0, stream>>>(src, dst, out_cnt, in_cnt);
  k_norms<<<(N_NODES + 255) / 256, 256, 0, stream>>>(out_cnt, in_cnt, out_norm, in_norm);
  k_conv <<<M_PAD, 256, 0, stream>>>(in_feat, out_norm, xb);
  k_scan1<<<NCH, SCAN_CH, 0, stream>>>(in_cnt, incl, partial);
  k_scan2<<<1, 64, 0, stream>>>(partial, chunk_off, row_ptr);
  k_scan3<<<NCH, SCAN_CH, 0, stream>>>(in_cnt, incl, chunk_off, row_ptr, cursor);
  k_pad  <<<(N_NODES + 255) / 256, 256, 0, stream>>>(in_cnt, row_ptr, csr_src);
  k_fill <<<(N_EDGES + 255) / 256, 256, 0, stream>>>(src, dst, cursor, csr_src);
  k_w1t  <<<dim3(IN_DIM / 32, HID / 32), 256, 0, stream>>>(W1, W1t);
  k_agg1 <<<dim3(M_PAD / 2, NPANEL), 128, 0, stream>>>(xb, row_ptr, csr_src, in_norm, aggb);
  k_gemm1<<<NWG, 512, 0, stream>>>(aggb, W1t, b1, h1, colsum, colsq);
  k_bnfin<<<HID / 256, 256, 0, stream>>>(colsum, colsq, Wout, cw0, cw1, cw2, mrs);
  k_ct   <<<1, 256, 0, stream>>>(mrs, Wout, ct);
  k_tmat <<<N_NODES, 256, 0, stream>>>(h1, cw0, cw1, cw2, ct, out_norm, t4);
  k_out  <<<(N_NODES + 255) / 256, 256, 0, stream>>>(row_ptr, csr_src, t4, in_norm, bout, out);
}